// Round 7
// baseline (609.099 us; speedup 1.0000x reference)
//
#include <hip/hip_runtime.h>
#include <stdint.h>

// Problem constants
#define BB    2
#define T_SEQ 2048
#define NH    16
#define DH    128
#define DM    2048   // N_HEADS * D_HEAD

typedef unsigned short u16;
typedef unsigned int   u32;
typedef __attribute__((ext_vector_type(8))) short short8;
typedef __attribute__((ext_vector_type(4))) short short4_t;
typedef __attribute__((ext_vector_type(4))) float floatx4;

__device__ __forceinline__ float bf2f(u16 b) { return __uint_as_float(((u32)b) << 16); }
__device__ __forceinline__ u16 f2bf(float f) {
    u32 u = __float_as_uint(f);
    u32 r = u + 0x7fffu + ((u >> 16) & 1u);   // round-nearest-even
    return (u16)(r >> 16);
}

// Convert 8 consecutive fp32 -> short8 of bf16 bits (RNE)
__device__ __forceinline__ short8 cvt8(const float* p) {
    floatx4 a = *(const floatx4*)p;
    floatx4 b = *(const floatx4*)(p + 4);
    short8 r;
    r[0] = (short)f2bf(a[0]); r[1] = (short)f2bf(a[1]);
    r[2] = (short)f2bf(a[2]); r[3] = (short)f2bf(a[3]);
    r[4] = (short)f2bf(b[0]); r[5] = (short)f2bf(b[1]);
    r[6] = (short)f2bf(b[2]); r[7] = (short)f2bf(b[3]);
    return r;
}

// async global->LDS 16B: LDS dest is wave-uniform base + lane*16
__device__ __forceinline__ void gl2lds16(const u16* g, u16* l) {
    __builtin_amdgcn_global_load_lds(
        (const __attribute__((address_space(1))) void*)g,
        (__attribute__((address_space(3))) void*)l, 16, 0, 0);
}

// ---------------------------------------------------------------------------
// Input-dtype guard (flag=1 -> fp32 inputs; proven on this dataset, round 3).
// ---------------------------------------------------------------------------
__global__ void detect_dtype(const u16* __restrict__ w, int* __restrict__ flag) {
    __shared__ int cnt;
    if (threadIdx.x == 0) cnt = 0;
    __syncthreads();
    int c = 0;
    for (int i = threadIdx.x; i < 2048; i += 256) {
        float v = bf2f(w[i]);
        if (!(fabsf(v) <= 1.0f)) c++;
    }
    atomicAdd(&cnt, c);
    __syncthreads();
    if (threadIdx.x == 0) *flag = (cnt > 64) ? 1 : 0;
}

// diagnostic only (flag==0 never fires on this dataset)
__global__ void sentinel_k(const int* __restrict__ flag, float* __restrict__ out, int n) {
    if (*flag != 0) return;
    for (int i = threadIdx.x; i < n; i += 256) out[i] = (i == 0) ? 200.0f : 0.0f;
}

__global__ void fill_const(float* __restrict__ out, int n, float v0) {
    int i = blockIdx.x * 256 + threadIdx.x;
    if (i < n) out[i] = (i == 0) ? v0 : 0.0f;
}

// fp32 -> bf16 bulk convert, 4 els/thread
__global__ __launch_bounds__(256) void cvt_f32_bf16(const float* __restrict__ src,
                                                    u16* __restrict__ dst, int n4,
                                                    const int* __restrict__ flag) {
    if (*flag == 0) return;
    int i = blockIdx.x * 256 + threadIdx.x;
    if (i < n4) {
        floatx4 v = ((const floatx4*)src)[i];
        short4_t r;
        r[0] = (short)f2bf(v[0]); r[1] = (short)f2bf(v[1]);
        r[2] = (short)f2bf(v[2]); r[3] = (short)f2bf(v[3]);
        ((short4_t*)dst)[i] = r;
    }
}

// ---------------------------------------------------------------------------
// FAST GEMM (m97 structure): C[M,N] = A[M,K]*B[N,K]^T, bf16 inputs via
// global_load_lds width-16 staging. 128x128 tile, BK=32, 4 waves x 64x64.
// PERM=0: plain row-major out (fp32 if OF32).
// PERM=3: fused-QKV routing — block-uniform slice = rowB0>>11:
//         0,1 -> (B,H,T,D) at C + slice*8388608 ; 2 -> (B,H,D,T') w/ key perm.
// ---------------------------------------------------------------------------
template<int PERM, int OF32>
__global__ __launch_bounds__(256) void gemm97(const u16* __restrict__ A,
                                              const u16* __restrict__ B,
                                              void* __restrict__ Cv,
                                              const int* __restrict__ flag,
                                              int M, int N, int K)
{
    if (*flag == 0) return;

    __shared__ __align__(16) u16 As[128 * 32];
    __shared__ __align__(16) u16 Bs[128 * 32];

    u16*   C16 = (u16*)Cv;
    float* C32 = (float*)Cv;

    const int tid  = threadIdx.x;
    const int lane = tid & 63;
    const int quad = lane >> 4;
    const int l15  = lane & 15;
    const int wave = tid >> 6;
    const int wy   = (wave >> 1) * 64;
    const int wx   = (wave & 1) * 64;
    const int rowA0 = blockIdx.y * 128;
    const int rowB0 = blockIdx.x * 128;

    const int lrow = lane >> 2;
    const int lcol = (lane & 3) << 3;
    const int segA0 = wave * 2, segA1 = wave * 2 + 1;

    const u16* gA0 = A + (size_t)(rowA0 + segA0 * 16 + lrow) * K + lcol;
    const u16* gA1 = A + (size_t)(rowA0 + segA1 * 16 + lrow) * K + lcol;
    const u16* gB0 = B + (size_t)(rowB0 + segA0 * 16 + lrow) * K + lcol;
    const u16* gB1 = B + (size_t)(rowB0 + segA1 * 16 + lrow) * K + lcol;
    u16* lA0 = &As[segA0 * 16 * 32];
    u16* lA1 = &As[segA1 * 16 * 32];
    u16* lB0 = &Bs[segA0 * 16 * 32];
    u16* lB1 = &Bs[segA1 * 16 * 32];

    floatx4 acc[4][4];
#pragma unroll
    for (int i = 0; i < 4; ++i)
#pragma unroll
        for (int j = 0; j < 4; ++j) acc[i][j] = (floatx4){0.f, 0.f, 0.f, 0.f};

    for (int k0 = 0; k0 < K; k0 += 32) {
        __syncthreads();
        gl2lds16(gA0 + k0, lA0);
        gl2lds16(gA1 + k0, lA1);
        gl2lds16(gB0 + k0, lB0);
        gl2lds16(gB1 + k0, lB1);
        __syncthreads();

        short8 a[4], b[4];
#pragma unroll
        for (int i = 0; i < 4; ++i)
            a[i] = *(const short8*)&As[(wy + i * 16 + l15) * 32 + quad * 8];
#pragma unroll
        for (int i = 0; i < 4; ++i)
            b[i] = *(const short8*)&Bs[(wx + i * 16 + l15) * 32 + quad * 8];
#pragma unroll
        for (int i = 0; i < 4; ++i)
#pragma unroll
            for (int j = 0; j < 4; ++j)
                acc[i][j] = __builtin_amdgcn_mfma_f32_16x16x32_bf16(a[i], b[j], acc[i][j], 0, 0, 0);
    }

#pragma unroll
    for (int i = 0; i < 4; ++i) {
#pragma unroll
        for (int j = 0; j < 4; ++j) {
#pragma unroll
            for (int r = 0; r < 4; ++r) {
                int row = rowA0 + wy + i * 16 + quad * 4 + r;
                int col = rowB0 + wx + j * 16 + l15;
                if (PERM == 3) {
                    int slice = rowB0 >> 11;              // block-uniform
                    u16* dbuf = C16 + (size_t)slice * 8388608;
                    int b_ = row >> 11, t_ = row & 2047;
                    int colm = col & 2047;
                    int h_ = colm >> 7, d_ = colm & 127;
                    size_t dst;
                    if (slice < 2) {
                        dst = ((size_t)((b_ * NH + h_) * T_SEQ + t_)) * DH + d_;
                    } else {
                        int u  = t_ & 63;
                        int tp = (t_ & ~63) + ((u & 15) * 4) + (u >> 4);
                        dst = ((size_t)((b_ * NH + h_) * DH + d_)) * T_SEQ + tp;
                    }
                    dbuf[dst] = f2bf(acc[i][j][r]);
                } else {
                    size_t dst = (size_t)row * N + col;
                    if (OF32) C32[dst] = acc[i][j][r];
                    else      C16[dst] = f2bf(acc[i][j][r]);
                }
            }
        }
    }
}

// ---------------------------------------------------------------------------
// FALLBACK GEMM (register-staged, fp32 inputs converted in regs).
// ---------------------------------------------------------------------------
template<int PERM, int AF32, int BF32, int OF32>
__global__ __launch_bounds__(256) void gemm_bt(const void* __restrict__ Av,
                                               const void* __restrict__ Bv,
                                               void* __restrict__ Cv,
                                               const int* __restrict__ flag,
                                               int bslice, int M, int N, int K)
{
    if (*flag == 0) return;

    __shared__ __align__(16) u16 As[128 * 32];
    __shared__ __align__(16) u16 Bs[128 * 32];

    const u16*   A16 = (const u16*)Av;
    const float* A32 = (const float*)Av;
    const u16*   B16 = (const u16*)Bv   + (size_t)bslice * DM * DM;
    const float* B32 = (const float*)Bv + (size_t)bslice * DM * DM;
    u16*   C16 = (u16*)Cv;
    float* C32 = (float*)Cv;

    const int tid  = threadIdx.x;
    const int lane = tid & 63;
    const int quad = lane >> 4;
    const int l15  = lane & 15;
    const int wave = tid >> 6;
    const int wy   = (wave >> 1) * 64;
    const int wx   = (wave & 1) * 64;
    const int rowA0 = blockIdx.y * 128;
    const int rowB0 = blockIdx.x * 128;

    const int srow = tid >> 2;
    const int scol = (tid & 3) << 3;

    const size_t aoff0 = (size_t)(rowA0 + srow) * K + scol;
    const size_t aoff1 = aoff0 + (size_t)64 * K;
    const size_t boff0 = (size_t)(rowB0 + srow) * K + scol;
    const size_t boff1 = boff0 + (size_t)64 * K;

    u16* AsW0 = &As[srow * 32 + scol];
    u16* AsW1 = &As[(srow + 64) * 32 + scol];
    u16* BsW0 = &Bs[srow * 32 + scol];
    u16* BsW1 = &Bs[(srow + 64) * 32 + scol];

    floatx4 acc[4][4];
#pragma unroll
    for (int i = 0; i < 4; ++i)
#pragma unroll
        for (int j = 0; j < 4; ++j) acc[i][j] = (floatx4){0.f, 0.f, 0.f, 0.f};

    for (int k0 = 0; k0 < K; k0 += 32) {
        short8 av0 = AF32 ? cvt8(A32 + aoff0 + k0) : *(const short8*)(A16 + aoff0 + k0);
        short8 av1 = AF32 ? cvt8(A32 + aoff1 + k0) : *(const short8*)(A16 + aoff1 + k0);
        short8 bv0 = BF32 ? cvt8(B32 + boff0 + k0) : *(const short8*)(B16 + boff0 + k0);
        short8 bv1 = BF32 ? cvt8(B32 + boff1 + k0) : *(const short8*)(B16 + boff1 + k0);
        __syncthreads();
        *(short8*)AsW0 = av0;
        *(short8*)AsW1 = av1;
        *(short8*)BsW0 = bv0;
        *(short8*)BsW1 = bv1;
        __syncthreads();

        short8 a[4], b[4];
#pragma unroll
        for (int i = 0; i < 4; ++i)
            a[i] = *(const short8*)&As[(wy + i * 16 + l15) * 32 + quad * 8];
#pragma unroll
        for (int i = 0; i < 4; ++i)
            b[i] = *(const short8*)&Bs[(wx + i * 16 + l15) * 32 + quad * 8];
#pragma unroll
        for (int i = 0; i < 4; ++i)
#pragma unroll
            for (int j = 0; j < 4; ++j)
                acc[i][j] = __builtin_amdgcn_mfma_f32_16x16x32_bf16(a[i], b[j], acc[i][j], 0, 0, 0);
    }

#pragma unroll
    for (int i = 0; i < 4; ++i) {
#pragma unroll
        for (int j = 0; j < 4; ++j) {
#pragma unroll
            for (int r = 0; r < 4; ++r) {
                int row = rowA0 + wy + i * 16 + quad * 4 + r;
                int col = rowB0 + wx + j * 16 + l15;
                size_t dst;
                if (PERM == 1) {
                    int b_ = row >> 11, t_ = row & 2047;
                    int h_ = col >> 7,  d_ = col & 127;
                    dst = ((size_t)((b_ * NH + h_) * T_SEQ + t_)) * DH + d_;
                } else if (PERM == 2) {
                    int b_ = row >> 11, t_ = row & 2047;
                    int h_ = col >> 7,  d_ = col & 127;
                    int u  = t_ & 63;
                    int tp = (t_ & ~63) + ((u & 15) * 4) + (u >> 4);
                    dst = ((size_t)((b_ * NH + h_) * DH + d_)) * T_SEQ + tp;
                } else {
                    dst = (size_t)row * N + col;
                }
                if (OF32) C32[dst] = acc[i][j][r];
                else      C16[dst] = f2bf(acc[i][j][r]);
            }
        }
    }
}

// ---------------------------------------------------------------------------
// In-place RoPE on (B,H,T,D) bf16 q and k; q also gets gain*log2e/sqrt(D).
// ---------------------------------------------------------------------------
__global__ __launch_bounds__(256) void rope_inplace(u16* __restrict__ q,
                                                    u16* __restrict__ k,
                                                    const void* __restrict__ gainv,
                                                    const void* __restrict__ cosv,
                                                    const void* __restrict__ sinv,
                                                    const int* __restrict__ flag)
{
    if (*flag == 0) return;
    const float* gain = (const float*)gainv;
    const float* cosb = (const float*)cosv;
    const float* sinb = (const float*)sinv;

    int idx = blockIdx.x * 256 + threadIdx.x;   // (b,h,t,d2)
    int d2 = idx & 63;
    int t  = (idx >> 6) & 2047;
    int h  = (idx >> 17) & 15;
    int b  = idx >> 21;

    float c = cosb[t * 64 + d2];
    float s = sinb[t * 64 + d2];
    float g = gain[h] * 0.08838834764831843f * 1.4426950408889634f;

    size_t row = ((size_t)((b * NH + h) * T_SEQ + t)) * DH;
    float q1 = bf2f(q[row + d2]);
    float q2 = bf2f(q[row + 64 + d2]);
    q[row + d2]      = f2bf((q1 * c - q2 * s) * g);
    q[row + 64 + d2] = f2bf((q2 * c + q1 * s) * g);

    float k1 = bf2f(k[row + d2]);
    float k2 = bf2f(k[row + 64 + d2]);
    k[row + d2]      = f2bf(k1 * c - k2 * s);
    k[row + 64 + d2] = f2bf(k2 * c + k1 * s);
}

// ---------------------------------------------------------------------------
// MFMA flash attention (causal), PAIRED q-tiles for uniform work:
// block (p, bh) handles q-tiles A=p and B=31-p  ->  exactly 33 k-tile units.
// Shared Ks/Vt per stage; P packed for both tiles, then fused PV loop reads
// each V fragment once feeding two MFMAs. Register prefetch of next K/V.
//   q,k: (B,H,T,D) bf16    v: (B,H,D,T') bf16, key perm u'=(u&15)*4+(u>>4)
//   y: (B,T,C) bf16
// ---------------------------------------------------------------------------
__global__ __launch_bounds__(256) void attn_flash2(const u16* __restrict__ q,
                                                   const u16* __restrict__ k,
                                                   const u16* __restrict__ v,
                                                   u16* __restrict__ y,
                                                   const int* __restrict__ flag)
{
    if (*flag == 0) return;

    __shared__ __align__(16) u16 Ks[64 * 128];        // 16 KB
    __shared__ __align__(16) u16 Vt[128 * 64];        // 16 KB
    __shared__ __align__(16) u16 Ps[4][2][16 * 64];   // 16 KB (per-wave, 2 tiles)

    const int tid  = threadIdx.x;
    const int lane = tid & 63;
    const int l15  = lane & 15;
    const int quad = lane >> 4;
    const int wave = tid >> 6;
    const int bh   = blockIdx.y;
    const int p    = blockIdx.x;                      // 0..15
    const int qtA  = p;
    const int qtB  = (T_SEQ / 64 - 1) - p;            // 31-p
    const int q0A  = qtA * 64 + wave * 16;
    const int q0B  = qtB * 64 + wave * 16;

    const u16* kbase = k + (size_t)bh * T_SEQ * DH;
    const u16* vbase = v + (size_t)bh * DH * T_SEQ;

    short8 aqA[4], aqB[4];
    {
        const u16* qra = q + ((size_t)bh * T_SEQ + q0A + l15) * DH + quad * 8;
        const u16* qrb = q + ((size_t)bh * T_SEQ + q0B + l15) * DH + quad * 8;
#pragma unroll
        for (int s = 0; s < 4; ++s) { aqA[s] = *(const short8*)(qra + s * 32);
                                      aqB[s] = *(const short8*)(qrb + s * 32); }
    }

    floatx4 oA[8], oB[8];
#pragma unroll
    for (int n = 0; n < 8; ++n) { oA[n] = (floatx4){0.f,0.f,0.f,0.f};
                                  oB[n] = (floatx4){0.f,0.f,0.f,0.f}; }
    float mA[4] = {-1e30f,-1e30f,-1e30f,-1e30f}, lA[4] = {0.f,0.f,0.f,0.f};
    float mB[4] = {-1e30f,-1e30f,-1e30f,-1e30f}, lB[4] = {0.f,0.f,0.f,0.f};

    const int iters = qtB + 1;                        // 32 - p

    const int skey = tid >> 2;
    const int sg4  = (tid & 3) * 4;
    const int vdim = tid >> 1;
    const int vg4  = (tid & 1) * 4;

#define LOADKV(KT, KR, VR) do {                                               \
        const u16* kg_ = kbase + ((size_t)((KT) * 64 + skey)) * DH + sg4 * 8; \
        const u16* vg_ = vbase + (size_t)vdim * T_SEQ + (KT) * 64 + vg4 * 8;  \
        _Pragma("unroll")                                                     \
        for (int i_ = 0; i_ < 4; ++i_) KR[i_] = *(const short8*)(kg_ + i_ * 8); \
        _Pragma("unroll")                                                     \
        for (int i_ = 0; i_ < 4; ++i_) VR[i_] = *(const short8*)(vg_ + i_ * 8); \
    } while (0)

    short8 krA[4], vrA[4], krB[4], vrB[4];
    LOADKV(0, krA, vrA);

    // S + softmax + pack for one q-tile (block-uniform calls)
    auto process = [&](const short8 (&aq)[4], float (&m_)[4], float (&l_)[4],
                       floatx4 (&o)[8], int q0, bool dg, int kt, int which) {
        floatx4 sc[4];
#pragma unroll
        for (int t = 0; t < 4; ++t) {
            sc[t] = (floatx4){0.f, 0.f, 0.f, 0.f};
#pragma unroll
            for (int s = 0; s < 4; ++s) {
                short8 bk = *(const short8*)&Ks[(t * 16 + l15) * 128 +
                                                (((s * 4 + quad) ^ (l15 & 7)) << 3)];
                sc[t] = __builtin_amdgcn_mfma_f32_16x16x32_bf16(aq[s], bk, sc[t], 0, 0, 0);
            }
        }
#pragma unroll
        for (int r = 0; r < 4; ++r) {
            const int qrow = q0 + quad * 4 + r;
            float vt[4];
            float mx = m_[r];
#pragma unroll
            for (int t = 0; t < 4; ++t) {
                float s_ = sc[t][r];
                if (dg && (kt * 64 + t * 16 + l15 > qrow)) s_ = -1e30f;
                vt[t] = s_;
                mx = fmaxf(mx, s_);
            }
            mx = fmaxf(mx, __shfl_xor(mx, 1));
            mx = fmaxf(mx, __shfl_xor(mx, 2));
            mx = fmaxf(mx, __shfl_xor(mx, 4));
            mx = fmaxf(mx, __shfl_xor(mx, 8));
            float al = exp2f(m_[r] - mx);
            m_[r] = mx;
            float rs = 0.f;
            float p0 = exp2f(vt[0] - mx), p1 = exp2f(vt[1] - mx);
            float p2 = exp2f(vt[2] - mx), p3 = exp2f(vt[3] - mx);
            rs = p0 + p1 + p2 + p3;
            rs += __shfl_xor(rs, 1);
            rs += __shfl_xor(rs, 2);
            rs += __shfl_xor(rs, 4);
            rs += __shfl_xor(rs, 8);
            l_[r] = l_[r] * al + rs;
#pragma unroll
            for (int n = 0; n < 8; ++n) o[n][r] *= al;

            int qr = quad * 4 + r;
            u32 lo = (u32)f2bf(p0) | ((u32)f2bf(p1) << 16);
            u32 hi = (u32)f2bf(p2) | ((u32)f2bf(p3) << 16);
            u32* dst = (u32*)&Ps[wave][which][qr * 64 +
                                             (((l15 >> 1) ^ (qr & 7)) << 3) + (l15 & 1) * 4];
            dst[0] = lo;
            dst[1] = hi;
        }
    };

    for (int kt = 0; kt < iters; ++kt) {
        __syncthreads();
#pragma unroll
        for (int i = 0; i < 4; ++i)
            *(short8*)&Ks[skey * 128 + (((sg4 + i) ^ (skey & 7)) << 3)] = krA[i];
#pragma unroll
        for (int i = 0; i < 4; ++i)
            *(short8*)&Vt[vdim * 64 + (((vg4 + i) ^ (vdim & 7)) << 3)] = vrA[i];
        __syncthreads();

        if (kt + 1 < iters) LOADKV(kt + 1, krB, vrB);

        const bool actA = (kt <= qtA);                // block-uniform
        process(aqB, mB, lB, oB, q0B, kt == qtB, kt, 0);
        if (actA) process(aqA, mA, lA, oA, q0A, kt == qtA, kt, 1);

        // fused PV: read each V fragment once, feed both tiles
#pragma unroll
        for (int s = 0; s < 2; ++s) {
            short8 apB = *(const short8*)&Ps[wave][0][l15 * 64 +
                                                      (((s * 4 + quad) ^ (l15 & 7)) << 3)];
            short8 apA;
            if (actA) apA = *(const short8*)&Ps[wave][1][l15 * 64 +
                                                         (((s * 4 + quad) ^ (l15 & 7)) << 3)];
#pragma unroll
            for (int n = 0; n < 8; ++n) {
                short8 bv = *(const short8*)&Vt[(n * 16 + l15) * 64 +
                                                (((s * 4 + quad) ^ (l15 & 7)) << 3)];
                oB[n] = __builtin_amdgcn_mfma_f32_16x16x32_bf16(apB, bv, oB[n], 0, 0, 0);
                if (actA)
                    oA[n] = __builtin_amdgcn_mfma_f32_16x16x32_bf16(apA, bv, oA[n], 0, 0, 0);
            }
        }

#pragma unroll
        for (int i = 0; i < 4; ++i) { krA[i] = krB[i]; vrA[i] = vrB[i]; }
    }
#undef LOADKV

    const int b_ = bh >> 4, h_ = bh & 15;
#pragma unroll
    for (int r = 0; r < 4; ++r) {
        float invB = 1.f / lB[r];
        float invA = 1.f / lA[r];
        int rowB = q0B + quad * 4 + r;
        int rowA = q0A + quad * 4 + r;
        size_t yoB = ((size_t)(b_ * T_SEQ + rowB)) * DM + h_ * DH + l15;
        size_t yoA = ((size_t)(b_ * T_SEQ + rowA)) * DM + h_ * DH + l15;
#pragma unroll
        for (int n = 0; n < 8; ++n) {
            y[yoB + n * 16] = f2bf(oB[n][r] * invB);
            y[yoA + n * 16] = f2bf(oA[n][r] * invA);
        }
    }
}

// ---------------------------------------------------------------------------
extern "C" void kernel_launch(void* const* d_in, const int* in_sizes, int n_in,
                              void* d_out, int out_size, void* d_ws, size_t ws_size,
                              hipStream_t stream)
{
    float* out = (float*)d_out;
    const int FILLB = (out_size + 255) / 256;

    bool ok = (n_in == 6) &&
              in_sizes[0] == 8388608 && in_sizes[1] == 12582912 &&
              in_sizes[2] == 4194304 && in_sizes[3] == 16 &&
              in_sizes[4] == 131072  && in_sizes[5] == 131072 &&
              out_size == 8388608;
    if (!ok) {
        fill_const<<<FILLB, 256, 0, stream>>>(out, out_size, 150.0f);
        return;
    }

    const size_t MB = 1024 * 1024;
    const size_t BUF = 16 * MB;
    if (ws_size < 4 * BUF + 256) {
        fill_const<<<FILLB, 256, 0, stream>>>(out, out_size, 100.0f);
        return;
    }

    const void* x     = d_in[0];
    const void* Wqkv  = d_in[1];
    const void* Wproj = d_in[2];
    const void* qgain = d_in[3];
    const void* rc    = d_in[4];
    const void* rs    = d_in[5];

    char* ws = (char*)d_ws;
    const size_t FAST_NEED = 96 * MB + 256;

    if (ws_size >= FAST_NEED) {
        u16* qb   = (u16*)(ws);
        u16* kb   = (u16*)(ws + BUF);
        u16* vb   = (u16*)(ws + 2 * BUF);
        u16* wqbf = (u16*)(ws + 3 * BUF);
        u16* wpbf = (u16*)(ws + 3 * BUF + 24 * MB);
        u16* xbf  = (u16*)(ws + 5 * BUF);
        u16* yb   = xbf;                            // alias: x dead after QKV
        int* flag = (int*)(ws + 6 * BUF);

        detect_dtype<<<1, 256, 0, stream>>>((const u16*)Wqkv, flag);

        cvt_f32_bf16<<<(8388608 / 4 + 255) / 256, 256, 0, stream>>>((const float*)x, xbf, 8388608 / 4, flag);
        cvt_f32_bf16<<<(12582912 / 4 + 255) / 256, 256, 0, stream>>>((const float*)Wqkv, wqbf, 12582912 / 4, flag);
        cvt_f32_bf16<<<(4194304 / 4 + 255) / 256, 256, 0, stream>>>((const float*)Wproj, wpbf, 4194304 / 4, flag);

        gemm97<3, 0><<<dim3(48, 32), 256, 0, stream>>>(xbf, wqbf, qb, flag, 4096, 6144, 2048);
        rope_inplace<<<16384, 256, 0, stream>>>(qb, kb, qgain, rc, rs, flag);
        attn_flash2<<<dim3(T_SEQ / 128, BB * NH), 256, 0, stream>>>(qb, kb, vb, yb, flag);
        gemm97<0, 1><<<dim3(16, 32), 256, 0, stream>>>(yb, wpbf, out, flag, 4096, 2048, 2048);
        sentinel_k<<<1, 256, 0, stream>>>(flag, out, out_size);
    } else {
        u16* qb = (u16*)(ws);
        u16* kb = (u16*)(ws + BUF);
        u16* vb = (u16*)(ws + 2 * BUF);
        u16* yb = (u16*)(ws + 3 * BUF);
        int* flag = (int*)(ws + 4 * BUF);

        detect_dtype<<<1, 256, 0, stream>>>((const u16*)Wqkv, flag);
        gemm_bt<1, 1, 1, 0><<<dim3(16, 32), 256, 0, stream>>>(x, Wqkv, qb, flag, 0, 4096, 2048, 2048);
        gemm_bt<1, 1, 1, 0><<<dim3(16, 32), 256, 0, stream>>>(x, Wqkv, kb, flag, 1, 4096, 2048, 2048);
        gemm_bt<2, 1, 1, 0><<<dim3(16, 32), 256, 0, stream>>>(x, Wqkv, vb, flag, 2, 4096, 2048, 2048);
        rope_inplace<<<16384, 256, 0, stream>>>(qb, kb, qgain, rc, rs, flag);
        attn_flash2<<<dim3(T_SEQ / 128, BB * NH), 256, 0, stream>>>(qb, kb, vb, yb, flag);
        gemm_bt<0, 0, 1, 1><<<dim3(16, 32), 256, 0, stream>>>(yb, Wproj, out, flag, 0, 4096, 2048, 2048);
        sentinel_k<<<1, 256, 0, stream>>>(flag, out, out_size);
    }
}

// Round 8
// 523.961 us; speedup vs baseline: 1.1625x; 1.1625x over previous
//
#include <hip/hip_runtime.h>
#include <stdint.h>

// Problem constants
#define BB    2
#define T_SEQ 2048
#define NH    16
#define DH    128
#define DM    2048   // N_HEADS * D_HEAD

typedef unsigned short u16;
typedef unsigned int   u32;
typedef __attribute__((ext_vector_type(8))) short short8;
typedef __attribute__((ext_vector_type(4))) short short4_t;
typedef __attribute__((ext_vector_type(4))) float floatx4;

__device__ __forceinline__ float bf2f(u16 b) { return __uint_as_float(((u32)b) << 16); }
__device__ __forceinline__ u16 f2bf(float f) {
    u32 u = __float_as_uint(f);
    u32 r = u + 0x7fffu + ((u >> 16) & 1u);   // round-nearest-even
    return (u16)(r >> 16);
}

// Convert 8 consecutive fp32 -> short8 of bf16 bits (RNE)
__device__ __forceinline__ short8 cvt8(const float* p) {
    floatx4 a = *(const floatx4*)p;
    floatx4 b = *(const floatx4*)(p + 4);
    short8 r;
    r[0] = (short)f2bf(a[0]); r[1] = (short)f2bf(a[1]);
    r[2] = (short)f2bf(a[2]); r[3] = (short)f2bf(a[3]);
    r[4] = (short)f2bf(b[0]); r[5] = (short)f2bf(b[1]);
    r[6] = (short)f2bf(b[2]); r[7] = (short)f2bf(b[3]);
    return r;
}

// async global->LDS 16B: LDS dest is wave-uniform base + lane*16
__device__ __forceinline__ void gl2lds16(const u16* g, u16* l) {
    __builtin_amdgcn_global_load_lds(
        (const __attribute__((address_space(1))) void*)g,
        (__attribute__((address_space(3))) void*)l, 16, 0, 0);
}

// ---------------------------------------------------------------------------
// Input-dtype guard (flag=1 -> fp32 inputs; proven on this dataset, round 3).
// ---------------------------------------------------------------------------
__global__ void detect_dtype(const u16* __restrict__ w, int* __restrict__ flag) {
    __shared__ int cnt;
    if (threadIdx.x == 0) cnt = 0;
    __syncthreads();
    int c = 0;
    for (int i = threadIdx.x; i < 2048; i += 256) {
        float v = bf2f(w[i]);
        if (!(fabsf(v) <= 1.0f)) c++;
    }
    atomicAdd(&cnt, c);
    __syncthreads();
    if (threadIdx.x == 0) *flag = (cnt > 64) ? 1 : 0;
}

// diagnostic only (flag==0 never fires on this dataset)
__global__ void sentinel_k(const int* __restrict__ flag, float* __restrict__ out, int n) {
    if (*flag != 0) return;
    for (int i = threadIdx.x; i < n; i += 256) out[i] = (i == 0) ? 200.0f : 0.0f;
}

__global__ void fill_const(float* __restrict__ out, int n, float v0) {
    int i = blockIdx.x * 256 + threadIdx.x;
    if (i < n) out[i] = (i == 0) ? v0 : 0.0f;
}

// fp32 -> bf16 bulk convert, 4 els/thread
__global__ __launch_bounds__(256) void cvt_f32_bf16(const float* __restrict__ src,
                                                    u16* __restrict__ dst, int n4,
                                                    const int* __restrict__ flag) {
    if (*flag == 0) return;
    int i = blockIdx.x * 256 + threadIdx.x;
    if (i < n4) {
        floatx4 v = ((const floatx4*)src)[i];
        short4_t r;
        r[0] = (short)f2bf(v[0]); r[1] = (short)f2bf(v[1]);
        r[2] = (short)f2bf(v[2]); r[3] = (short)f2bf(v[3]);
        ((short4_t*)dst)[i] = r;
    }
}

// ---------------------------------------------------------------------------
// FAST GEMM (m97 structure): C[M,N] = A[M,K]*B[N,K]^T, bf16 inputs via
// global_load_lds width-16 staging. 128x128 tile, BK=32, 4 waves x 64x64.
// PERM=0: plain row-major out (fp32 if OF32).
// PERM=3: fused-QKV routing — block-uniform slice = rowB0>>11:
//         0,1 -> (B,H,T,D) at C + slice*8388608 ; 2 -> (B,H,D,T') w/ key perm.
// ---------------------------------------------------------------------------
template<int PERM, int OF32>
__global__ __launch_bounds__(256) void gemm97(const u16* __restrict__ A,
                                              const u16* __restrict__ B,
                                              void* __restrict__ Cv,
                                              const int* __restrict__ flag,
                                              int M, int N, int K)
{
    if (*flag == 0) return;

    __shared__ __align__(16) u16 As[128 * 32];
    __shared__ __align__(16) u16 Bs[128 * 32];

    u16*   C16 = (u16*)Cv;
    float* C32 = (float*)Cv;

    const int tid  = threadIdx.x;
    const int lane = tid & 63;
    const int quad = lane >> 4;
    const int l15  = lane & 15;
    const int wave = tid >> 6;
    const int wy   = (wave >> 1) * 64;
    const int wx   = (wave & 1) * 64;
    const int rowA0 = blockIdx.y * 128;
    const int rowB0 = blockIdx.x * 128;

    const int lrow = lane >> 2;
    const int lcol = (lane & 3) << 3;
    const int segA0 = wave * 2, segA1 = wave * 2 + 1;

    const u16* gA0 = A + (size_t)(rowA0 + segA0 * 16 + lrow) * K + lcol;
    const u16* gA1 = A + (size_t)(rowA0 + segA1 * 16 + lrow) * K + lcol;
    const u16* gB0 = B + (size_t)(rowB0 + segA0 * 16 + lrow) * K + lcol;
    const u16* gB1 = B + (size_t)(rowB0 + segA1 * 16 + lrow) * K + lcol;
    u16* lA0 = &As[segA0 * 16 * 32];
    u16* lA1 = &As[segA1 * 16 * 32];
    u16* lB0 = &Bs[segA0 * 16 * 32];
    u16* lB1 = &Bs[segA1 * 16 * 32];

    floatx4 acc[4][4];
#pragma unroll
    for (int i = 0; i < 4; ++i)
#pragma unroll
        for (int j = 0; j < 4; ++j) acc[i][j] = (floatx4){0.f, 0.f, 0.f, 0.f};

    for (int k0 = 0; k0 < K; k0 += 32) {
        __syncthreads();
        gl2lds16(gA0 + k0, lA0);
        gl2lds16(gA1 + k0, lA1);
        gl2lds16(gB0 + k0, lB0);
        gl2lds16(gB1 + k0, lB1);
        __syncthreads();

        short8 a[4], b[4];
#pragma unroll
        for (int i = 0; i < 4; ++i)
            a[i] = *(const short8*)&As[(wy + i * 16 + l15) * 32 + quad * 8];
#pragma unroll
        for (int i = 0; i < 4; ++i)
            b[i] = *(const short8*)&Bs[(wx + i * 16 + l15) * 32 + quad * 8];
#pragma unroll
        for (int i = 0; i < 4; ++i)
#pragma unroll
            for (int j = 0; j < 4; ++j)
                acc[i][j] = __builtin_amdgcn_mfma_f32_16x16x32_bf16(a[i], b[j], acc[i][j], 0, 0, 0);
    }

#pragma unroll
    for (int i = 0; i < 4; ++i) {
#pragma unroll
        for (int j = 0; j < 4; ++j) {
#pragma unroll
            for (int r = 0; r < 4; ++r) {
                int row = rowA0 + wy + i * 16 + quad * 4 + r;
                int col = rowB0 + wx + j * 16 + l15;
                if (PERM == 3) {
                    int slice = rowB0 >> 11;              // block-uniform
                    u16* dbuf = C16 + (size_t)slice * 8388608;
                    int b_ = row >> 11, t_ = row & 2047;
                    int colm = col & 2047;
                    int h_ = colm >> 7, d_ = colm & 127;
                    size_t dst;
                    if (slice < 2) {
                        dst = ((size_t)((b_ * NH + h_) * T_SEQ + t_)) * DH + d_;
                    } else {
                        int u  = t_ & 63;
                        int tp = (t_ & ~63) + ((u & 15) * 4) + (u >> 4);
                        dst = ((size_t)((b_ * NH + h_) * DH + d_)) * T_SEQ + tp;
                    }
                    dbuf[dst] = f2bf(acc[i][j][r]);
                } else {
                    size_t dst = (size_t)row * N + col;
                    if (OF32) C32[dst] = acc[i][j][r];
                    else      C16[dst] = f2bf(acc[i][j][r]);
                }
            }
        }
    }
}

// ---------------------------------------------------------------------------
// FALLBACK GEMM (register-staged, fp32 inputs converted in regs).
// ---------------------------------------------------------------------------
template<int PERM, int AF32, int BF32, int OF32>
__global__ __launch_bounds__(256) void gemm_bt(const void* __restrict__ Av,
                                               const void* __restrict__ Bv,
                                               void* __restrict__ Cv,
                                               const int* __restrict__ flag,
                                               int bslice, int M, int N, int K)
{
    if (*flag == 0) return;

    __shared__ __align__(16) u16 As[128 * 32];
    __shared__ __align__(16) u16 Bs[128 * 32];

    const u16*   A16 = (const u16*)Av;
    const float* A32 = (const float*)Av;
    const u16*   B16 = (const u16*)Bv   + (size_t)bslice * DM * DM;
    const float* B32 = (const float*)Bv + (size_t)bslice * DM * DM;
    u16*   C16 = (u16*)Cv;
    float* C32 = (float*)Cv;

    const int tid  = threadIdx.x;
    const int lane = tid & 63;
    const int quad = lane >> 4;
    const int l15  = lane & 15;
    const int wave = tid >> 6;
    const int wy   = (wave >> 1) * 64;
    const int wx   = (wave & 1) * 64;
    const int rowA0 = blockIdx.y * 128;
    const int rowB0 = blockIdx.x * 128;

    const int srow = tid >> 2;
    const int scol = (tid & 3) << 3;

    const size_t aoff0 = (size_t)(rowA0 + srow) * K + scol;
    const size_t aoff1 = aoff0 + (size_t)64 * K;
    const size_t boff0 = (size_t)(rowB0 + srow) * K + scol;
    const size_t boff1 = boff0 + (size_t)64 * K;

    u16* AsW0 = &As[srow * 32 + scol];
    u16* AsW1 = &As[(srow + 64) * 32 + scol];
    u16* BsW0 = &Bs[srow * 32 + scol];
    u16* BsW1 = &Bs[(srow + 64) * 32 + scol];

    floatx4 acc[4][4];
#pragma unroll
    for (int i = 0; i < 4; ++i)
#pragma unroll
        for (int j = 0; j < 4; ++j) acc[i][j] = (floatx4){0.f, 0.f, 0.f, 0.f};

    for (int k0 = 0; k0 < K; k0 += 32) {
        short8 av0 = AF32 ? cvt8(A32 + aoff0 + k0) : *(const short8*)(A16 + aoff0 + k0);
        short8 av1 = AF32 ? cvt8(A32 + aoff1 + k0) : *(const short8*)(A16 + aoff1 + k0);
        short8 bv0 = BF32 ? cvt8(B32 + boff0 + k0) : *(const short8*)(B16 + boff0 + k0);
        short8 bv1 = BF32 ? cvt8(B32 + boff1 + k0) : *(const short8*)(B16 + boff1 + k0);
        __syncthreads();
        *(short8*)AsW0 = av0;
        *(short8*)AsW1 = av1;
        *(short8*)BsW0 = bv0;
        *(short8*)BsW1 = bv1;
        __syncthreads();

        short8 a[4], b[4];
#pragma unroll
        for (int i = 0; i < 4; ++i)
            a[i] = *(const short8*)&As[(wy + i * 16 + l15) * 32 + quad * 8];
#pragma unroll
        for (int i = 0; i < 4; ++i)
            b[i] = *(const short8*)&Bs[(wx + i * 16 + l15) * 32 + quad * 8];
#pragma unroll
        for (int i = 0; i < 4; ++i)
#pragma unroll
            for (int j = 0; j < 4; ++j)
                acc[i][j] = __builtin_amdgcn_mfma_f32_16x16x32_bf16(a[i], b[j], acc[i][j], 0, 0, 0);
    }

#pragma unroll
    for (int i = 0; i < 4; ++i) {
#pragma unroll
        for (int j = 0; j < 4; ++j) {
#pragma unroll
            for (int r = 0; r < 4; ++r) {
                int row = rowA0 + wy + i * 16 + quad * 4 + r;
                int col = rowB0 + wx + j * 16 + l15;
                size_t dst;
                if (PERM == 1) {
                    int b_ = row >> 11, t_ = row & 2047;
                    int h_ = col >> 7,  d_ = col & 127;
                    dst = ((size_t)((b_ * NH + h_) * T_SEQ + t_)) * DH + d_;
                } else if (PERM == 2) {
                    int b_ = row >> 11, t_ = row & 2047;
                    int h_ = col >> 7,  d_ = col & 127;
                    int u  = t_ & 63;
                    int tp = (t_ & ~63) + ((u & 15) * 4) + (u >> 4);
                    dst = ((size_t)((b_ * NH + h_) * DH + d_)) * T_SEQ + tp;
                } else {
                    dst = (size_t)row * N + col;
                }
                if (OF32) C32[dst] = acc[i][j][r];
                else      C16[dst] = f2bf(acc[i][j][r]);
            }
        }
    }
}

// ---------------------------------------------------------------------------
// In-place RoPE on (B,H,T,D) bf16 q and k; q also gets gain*log2e/sqrt(D).
// ---------------------------------------------------------------------------
__global__ __launch_bounds__(256) void rope_inplace(u16* __restrict__ q,
                                                    u16* __restrict__ k,
                                                    const void* __restrict__ gainv,
                                                    const void* __restrict__ cosv,
                                                    const void* __restrict__ sinv,
                                                    const int* __restrict__ flag)
{
    if (*flag == 0) return;
    const float* gain = (const float*)gainv;
    const float* cosb = (const float*)cosv;
    const float* sinb = (const float*)sinv;

    int idx = blockIdx.x * 256 + threadIdx.x;   // (b,h,t,d2)
    int d2 = idx & 63;
    int t  = (idx >> 6) & 2047;
    int h  = (idx >> 17) & 15;
    int b  = idx >> 21;

    float c = cosb[t * 64 + d2];
    float s = sinb[t * 64 + d2];
    float g = gain[h] * 0.08838834764831843f * 1.4426950408889634f;

    size_t row = ((size_t)((b * NH + h) * T_SEQ + t)) * DH;
    float q1 = bf2f(q[row + d2]);
    float q2 = bf2f(q[row + 64 + d2]);
    q[row + d2]      = f2bf((q1 * c - q2 * s) * g);
    q[row + 64 + d2] = f2bf((q2 * c + q1 * s) * g);

    float k1 = bf2f(k[row + d2]);
    float k2 = bf2f(k[row + 64 + d2]);
    k[row + d2]      = f2bf(k1 * c - k2 * s);
    k[row + 64 + d2] = f2bf(k2 * c + k1 * s);
}

// ---------------------------------------------------------------------------
// MFMA flash attention (causal), SEQUENTIAL paired q-tiles:
// block (p, bh) processes tile 31-p fully, then tile p, REUSING registers
// (one tile's state live at a time -> no VGPR cliff). 33 k-iters per block,
// uniform across the 512-block grid (no triangular tail).
// Softmax: wave-uniform running max M (valid since softmax is invariant to
// any M >= rowmax: it cancels in o/l), scalar-branch rescale skip when M
// unchanged. Register prefetch of next K/V tile.
//   q,k: (B,H,T,D) bf16    v: (B,H,D,T') bf16, key perm u'=(u&15)*4+(u>>4)
//   y: (B,T,C) bf16
// ---------------------------------------------------------------------------
__global__ __launch_bounds__(256) void attn_flash3(const u16* __restrict__ q,
                                                   const u16* __restrict__ k,
                                                   const u16* __restrict__ v,
                                                   u16* __restrict__ y,
                                                   const int* __restrict__ flag)
{
    if (*flag == 0) return;

    __shared__ __align__(16) u16 Ks[64 * 128];        // 16 KB
    __shared__ __align__(16) u16 Vt[128 * 64];        // 16 KB
    __shared__ __align__(16) u16 Ps[4][16 * 64];      // 8 KB (per-wave)

    const int tid  = threadIdx.x;
    const int lane = tid & 63;
    const int l15  = lane & 15;
    const int quad = lane >> 4;
    const int wave = tid >> 6;
    const int bh   = blockIdx.y;
    const int p    = blockIdx.x;                      // 0..15

    const u16* kbase = k + (size_t)bh * T_SEQ * DH;
    const u16* vbase = v + (size_t)bh * DH * T_SEQ;
    const int b_ = bh >> 4, h_ = bh & 15;

    const int skey = tid >> 2;
    const int sg4  = (tid & 3) * 4;
    const int vdim = tid >> 1;
    const int vg4  = (tid & 1) * 4;

#define LOADKV(KT, KR, VR) do {                                               \
        const u16* kg_ = kbase + ((size_t)((KT) * 64 + skey)) * DH + sg4 * 8; \
        const u16* vg_ = vbase + (size_t)vdim * T_SEQ + (KT) * 64 + vg4 * 8;  \
        _Pragma("unroll")                                                     \
        for (int i_ = 0; i_ < 4; ++i_) KR[i_] = *(const short8*)(kg_ + i_ * 8); \
        _Pragma("unroll")                                                     \
        for (int i_ = 0; i_ < 4; ++i_) VR[i_] = *(const short8*)(vg_ + i_ * 8); \
    } while (0)

    for (int phase = 0; phase < 2; ++phase) {
        const int qt  = phase ? p : (T_SEQ / 64 - 1 - p);   // 31-p then p
        const int q0w = qt * 64 + wave * 16;
        const int iters = qt + 1;

        // Q A-fragments for this tile
        short8 aq[4];
        {
            const u16* qrow = q + ((size_t)bh * T_SEQ + q0w + l15) * DH + quad * 8;
#pragma unroll
            for (int s = 0; s < 4; ++s) aq[s] = *(const short8*)(qrow + s * 32);
        }

        floatx4 o[8];
#pragma unroll
        for (int n = 0; n < 8; ++n) o[n] = (floatx4){0.f, 0.f, 0.f, 0.f};
        float M = -1e30f;                       // wave-uniform running max
        float l_r[4] = {0.f, 0.f, 0.f, 0.f};

        short8 krA[4], vrA[4], krB[4], vrB[4];
        LOADKV(0, krA, vrA);

        for (int kt = 0; kt < iters; ++kt) {
            __syncthreads();   // prior LDS consumers done (incl. prev phase)
#pragma unroll
            for (int i = 0; i < 4; ++i)
                *(short8*)&Ks[skey * 128 + (((sg4 + i) ^ (skey & 7)) << 3)] = krA[i];
#pragma unroll
            for (int i = 0; i < 4; ++i)
                *(short8*)&Vt[vdim * 64 + (((vg4 + i) ^ (vdim & 7)) << 3)] = vrA[i];
            __syncthreads();

            if (kt + 1 < iters) LOADKV(kt + 1, krB, vrB);

            // ---- S = Q K^T ----
            floatx4 sc[4];
#pragma unroll
            for (int t = 0; t < 4; ++t) {
                sc[t] = (floatx4){0.f, 0.f, 0.f, 0.f};
#pragma unroll
                for (int s = 0; s < 4; ++s) {
                    short8 bk = *(const short8*)&Ks[(t * 16 + l15) * 128 +
                                                    (((s * 4 + quad) ^ (l15 & 7)) << 3)];
                    sc[t] = __builtin_amdgcn_mfma_f32_16x16x32_bf16(aq[s], bk, sc[t], 0, 0, 0);
                }
            }

            // ---- diagonal mask, then wave-uniform max ----
            if (kt == qt) {
#pragma unroll
                for (int t = 0; t < 4; ++t)
#pragma unroll
                    for (int r = 0; r < 4; ++r)
                        if (kt * 64 + t * 16 + l15 > q0w + quad * 4 + r)
                            sc[t][r] = -1e30f;
            }
            float mloc = sc[0][0];
#pragma unroll
            for (int t = 0; t < 4; ++t)
#pragma unroll
                for (int r = 0; r < 4; ++r) mloc = fmaxf(mloc, sc[t][r]);
            mloc = fmaxf(mloc, __shfl_xor(mloc, 1));
            mloc = fmaxf(mloc, __shfl_xor(mloc, 2));
            mloc = fmaxf(mloc, __shfl_xor(mloc, 4));
            mloc = fmaxf(mloc, __shfl_xor(mloc, 8));
            mloc = fmaxf(mloc, __shfl_xor(mloc, 16));
            mloc = fmaxf(mloc, __shfl_xor(mloc, 32));
            float Mn = fmaxf(M, mloc);
            float al = exp2f(M - Mn);
            M = Mn;

            // scalar-branch rescale skip: al is lane-invariant
            if (__builtin_amdgcn_readfirstlane(__float_as_uint(al)) != 0x3f800000u) {
#pragma unroll
                for (int n = 0; n < 8; ++n)
#pragma unroll
                    for (int r = 0; r < 4; ++r) o[n][r] *= al;
#pragma unroll
                for (int r = 0; r < 4; ++r) l_r[r] *= al;
            }

            // ---- p = exp2(s - M), per-row sums, pack to LDS ----
#pragma unroll
            for (int r = 0; r < 4; ++r) {
                float p0 = exp2f(sc[0][r] - M);
                float p1 = exp2f(sc[1][r] - M);
                float p2 = exp2f(sc[2][r] - M);
                float p3 = exp2f(sc[3][r] - M);
                float rs = p0 + p1 + p2 + p3;
                rs += __shfl_xor(rs, 1);
                rs += __shfl_xor(rs, 2);
                rs += __shfl_xor(rs, 4);
                rs += __shfl_xor(rs, 8);
                l_r[r] += rs;

                int qr = quad * 4 + r;
                u32 lo = (u32)f2bf(p0) | ((u32)f2bf(p1) << 16);
                u32 hi = (u32)f2bf(p2) | ((u32)f2bf(p3) << 16);
                u32* dst = (u32*)&Ps[wave][qr * 64 +
                                           (((l15 >> 1) ^ (qr & 7)) << 3) + (l15 & 1) * 4];
                dst[0] = lo;
                dst[1] = hi;
            }

            // ---- O += P V ----
#pragma unroll
            for (int s = 0; s < 2; ++s) {
                short8 ap = *(const short8*)&Ps[wave][l15 * 64 +
                                                      (((s * 4 + quad) ^ (l15 & 7)) << 3)];
#pragma unroll
                for (int n = 0; n < 8; ++n) {
                    short8 bv = *(const short8*)&Vt[(n * 16 + l15) * 64 +
                                                    (((s * 4 + quad) ^ (l15 & 7)) << 3)];
                    o[n] = __builtin_amdgcn_mfma_f32_16x16x32_bf16(ap, bv, o[n], 0, 0, 0);
                }
            }

#pragma unroll
            for (int i = 0; i < 4; ++i) { krA[i] = krB[i]; vrA[i] = vrB[i]; }
        }

        // ---- epilogue for this tile ----
#pragma unroll
        for (int r = 0; r < 4; ++r) {
            float inv = 1.f / l_r[r];
            int qrow = q0w + quad * 4 + r;
            size_t yo = ((size_t)(b_ * T_SEQ + qrow)) * DM + h_ * DH + l15;
#pragma unroll
            for (int n = 0; n < 8; ++n)
                y[yo + n * 16] = f2bf(o[n][r] * inv);
        }
    }
#undef LOADKV
}

// ---------------------------------------------------------------------------
extern "C" void kernel_launch(void* const* d_in, const int* in_sizes, int n_in,
                              void* d_out, int out_size, void* d_ws, size_t ws_size,
                              hipStream_t stream)
{
    float* out = (float*)d_out;
    const int FILLB = (out_size + 255) / 256;

    bool ok = (n_in == 6) &&
              in_sizes[0] == 8388608 && in_sizes[1] == 12582912 &&
              in_sizes[2] == 4194304 && in_sizes[3] == 16 &&
              in_sizes[4] == 131072  && in_sizes[5] == 131072 &&
              out_size == 8388608;
    if (!ok) {
        fill_const<<<FILLB, 256, 0, stream>>>(out, out_size, 150.0f);
        return;
    }

    const size_t MB = 1024 * 1024;
    const size_t BUF = 16 * MB;
    if (ws_size < 4 * BUF + 256) {
        fill_const<<<FILLB, 256, 0, stream>>>(out, out_size, 100.0f);
        return;
    }

    const void* x     = d_in[0];
    const void* Wqkv  = d_in[1];
    const void* Wproj = d_in[2];
    const void* qgain = d_in[3];
    const void* rc    = d_in[4];
    const void* rs    = d_in[5];

    char* ws = (char*)d_ws;
    const size_t FAST_NEED = 96 * MB + 256;

    if (ws_size >= FAST_NEED) {
        u16* qb   = (u16*)(ws);
        u16* kb   = (u16*)(ws + BUF);
        u16* vb   = (u16*)(ws + 2 * BUF);
        u16* wqbf = (u16*)(ws + 3 * BUF);
        u16* wpbf = (u16*)(ws + 3 * BUF + 24 * MB);
        u16* xbf  = (u16*)(ws + 5 * BUF);
        u16* yb   = xbf;                            // alias: x dead after QKV
        int* flag = (int*)(ws + 6 * BUF);

        detect_dtype<<<1, 256, 0, stream>>>((const u16*)Wqkv, flag);

        cvt_f32_bf16<<<(8388608 / 4 + 255) / 256, 256, 0, stream>>>((const float*)x, xbf, 8388608 / 4, flag);
        cvt_f32_bf16<<<(12582912 / 4 + 255) / 256, 256, 0, stream>>>((const float*)Wqkv, wqbf, 12582912 / 4, flag);
        cvt_f32_bf16<<<(4194304 / 4 + 255) / 256, 256, 0, stream>>>((const float*)Wproj, wpbf, 4194304 / 4, flag);

        gemm97<3, 0><<<dim3(48, 32), 256, 0, stream>>>(xbf, wqbf, qb, flag, 4096, 6144, 2048);
        rope_inplace<<<16384, 256, 0, stream>>>(qb, kb, qgain, rc, rs, flag);
        attn_flash3<<<dim3(T_SEQ / 128, BB * NH), 256, 0, stream>>>(qb, kb, vb, yb, flag);
        gemm97<0, 1><<<dim3(16, 32), 256, 0, stream>>>(yb, wpbf, out, flag, 4096, 2048, 2048);
        sentinel_k<<<1, 256, 0, stream>>>(flag, out, out_size);
    } else {
        u16* qb = (u16*)(ws);
        u16* kb = (u16*)(ws + BUF);
        u16* vb = (u16*)(ws + 2 * BUF);
        u16* yb = (u16*)(ws + 3 * BUF);
        int* flag = (int*)(ws + 4 * BUF);

        detect_dtype<<<1, 256, 0, stream>>>((const u16*)Wqkv, flag);
        gemm_bt<1, 1, 1, 0><<<dim3(16, 32), 256, 0, stream>>>(x, Wqkv, qb, flag, 0, 4096, 2048, 2048);
        gemm_bt<1, 1, 1, 0><<<dim3(16, 32), 256, 0, stream>>>(x, Wqkv, kb, flag, 1, 4096, 2048, 2048);
        gemm_bt<2, 1, 1, 0><<<dim3(16, 32), 256, 0, stream>>>(x, Wqkv, vb, flag, 2, 4096, 2048, 2048);
        rope_inplace<<<16384, 256, 0, stream>>>(qb, kb, qgain, rc, rs, flag);
        attn_flash3<<<dim3(T_SEQ / 128, BB * NH), 256, 0, stream>>>(qb, kb, vb, yb, flag);
        gemm_bt<0, 0, 1, 1><<<dim3(16, 32), 256, 0, stream>>>(yb, Wproj, out, flag, 0, 4096, 2048, 2048);
        sentinel_k<<<1, 256, 0, stream>>>(flag, out, out_size);
    }
}